// Round 1
// baseline (503.397 us; speedup 1.0000x reference)
//
#include <hip/hip_runtime.h>
#include <cstdint>
#include <cstddef>

#define NEG_SLOPE 0.2f

__device__ __forceinline__ float elu_f(float x) {
    return x > 0.f ? x : expm1f(x);
}

// ---------------------------------------------------------------------------
// Encoder: h0 = elu(elu(x @ W1 + b1) @ W2 + b2), x:[N,8] -> [N,64]
// ---------------------------------------------------------------------------
__global__ void encoder_kernel(const float* __restrict__ x,
                               const float* __restrict__ W1, const float* __restrict__ b1,
                               const float* __restrict__ W2, const float* __restrict__ b2,
                               float* __restrict__ h0, int n_nodes) {
    int i = blockIdx.x * blockDim.x + threadIdx.x;
    if (i >= n_nodes) return;
    const float4* xp = (const float4*)(x + (size_t)i * 8);
    float4 x0 = xp[0], x1 = xp[1];
    float xi[8] = {x0.x, x0.y, x0.z, x0.w, x1.x, x1.y, x1.z, x1.w};
    float h1[32];
#pragma unroll
    for (int j = 0; j < 32; ++j) {
        float a = b1[j];
#pragma unroll
        for (int k = 0; k < 8; ++k) a += xi[k] * W1[k * 32 + j];
        h1[j] = elu_f(a);
    }
    float* dst = h0 + (size_t)i * 64;
    for (int j = 0; j < 64; ++j) {
        float a = b2[j];
#pragma unroll
        for (int k = 0; k < 32; ++k) a += h1[k] * W2[k * 64 + j];
        dst[j] = elu_f(a);
    }
}

// ---------------------------------------------------------------------------
// CSR build (by destination), reused across all 3 GAT layers.
// edge_index may arrive as int32 or as int64-viewed-as-int32 pairs; detect.
// ---------------------------------------------------------------------------
__device__ __forceinline__ bool ei_is_i64(const int* ei) {
    int acc = 0;
#pragma unroll
    for (int i = 0; i < 8; ++i) acc |= ei[2 * i + 1];
    return acc == 0;  // high words of small int64 values are all zero
}

__global__ void zero_kernel(int* p, int n) {
    int i = blockIdx.x * blockDim.x + threadIdx.x;
    if (i < n) p[i] = 0;
}

__global__ void count_kernel(const int* __restrict__ ei, int E, int Etot,
                             int* __restrict__ cnt) {
    int e = blockIdx.x * blockDim.x + threadIdx.x;
    if (e >= Etot) return;
    int d;
    if (e < E) {
        bool w = ei_is_i64(ei);
        d = w ? ei[2 * (size_t)(E + e)] : ei[E + e];
    } else {
        d = e - E;  // self loop
    }
    atomicAdd(&cnt[d], 1);
}

__global__ void scan_kernel(const int* __restrict__ cnt, int* __restrict__ rowptr,
                            int* __restrict__ cursor, int n) {
    __shared__ int sdata[1024];
    __shared__ int s_off;
    int t = threadIdx.x;
    if (t == 0) s_off = 0;
    __syncthreads();
    for (int base = 0; base < n; base += 1024) {
        int v = (base + t < n) ? cnt[base + t] : 0;
        sdata[t] = v;
        __syncthreads();
        for (int off = 1; off < 1024; off <<= 1) {
            int add = (t >= off) ? sdata[t - off] : 0;
            __syncthreads();
            sdata[t] += add;
            __syncthreads();
        }
        int incl = sdata[t];
        int off0 = s_off;
        if (base + t < n) {
            rowptr[base + t + 1] = off0 + incl;
            cursor[base + t] = off0 + incl - v;  // exclusive
        }
        __syncthreads();
        if (t == 1023) s_off = off0 + sdata[1023];
        __syncthreads();
    }
    if (t == 0) rowptr[0] = 0;
}

__global__ void fill_kernel(const int* __restrict__ ei, int E, int Etot,
                            int* __restrict__ cursor, int* __restrict__ col) {
    int e = blockIdx.x * blockDim.x + threadIdx.x;
    if (e >= Etot) return;
    int s, d;
    if (e < E) {
        bool w = ei_is_i64(ei);
        if (w) { s = ei[2 * (size_t)e]; d = ei[2 * (size_t)(E + e)]; }
        else   { s = ei[e];             d = ei[E + e]; }
    } else {
        s = d = e - E;
    }
    int pos = atomicAdd(&cursor[d], 1);
    col[pos] = s;
}

// ---------------------------------------------------------------------------
// GAT projection: hp = x @ W  ([N,64]x[64,256]), plus per-head attention dots
// a_src[n,h] = sum_c hp[n,h,c]*att_s[h,c], same for a_dst.
// Block = 256 threads = 8 nodes x 32 channel-groups (8 ch each).
// ---------------------------------------------------------------------------
__global__ __launch_bounds__(256) void gat_proj_kernel(
    const float* __restrict__ xin, const float* __restrict__ W,
    const float* __restrict__ att_s, const float* __restrict__ att_d,
    float* __restrict__ hp, float* __restrict__ asrc, float* __restrict__ adst,
    int n_nodes) {
    const int t = threadIdx.x;
    const int nl = t >> 5;   // local node 0..7
    const int cg = t & 31;   // channel group 0..31 (8 ch each)
    const int n0 = blockIdx.x * 8;
    __shared__ float xs[8][64];
    for (int i = t; i < 8 * 64; i += 256) {
        int nn = n0 + (i >> 6);
        xs[i >> 6][i & 63] = (nn < n_nodes) ? xin[(size_t)nn * 64 + (i & 63)] : 0.f;
    }
    __syncthreads();
    const int n = n0 + nl;
    float acc[8];
#pragma unroll
    for (int j = 0; j < 8; ++j) acc[j] = 0.f;
    const float* Wb = W + cg * 8;
    for (int k = 0; k < 64; ++k) {
        float xv = xs[nl][k];
        const float4* wp = (const float4*)(Wb + k * 256);
        float4 w0 = wp[0], w1 = wp[1];
        acc[0] += xv * w0.x; acc[1] += xv * w0.y;
        acc[2] += xv * w0.z; acc[3] += xv * w0.w;
        acc[4] += xv * w1.x; acc[5] += xv * w1.y;
        acc[6] += xv * w1.z; acc[7] += xv * w1.w;
    }
    if (n < n_nodes) {
        float4* op = (float4*)(hp + (size_t)n * 256 + cg * 8);
        op[0] = make_float4(acc[0], acc[1], acc[2], acc[3]);
        op[1] = make_float4(acc[4], acc[5], acc[6], acc[7]);
    }
    // attention partial dots; head h = cg>>3, channels cbase..cbase+7
    const int h = cg >> 3;
    const int cbase = (cg & 7) * 8;
    float ps = 0.f, pd = 0.f;
#pragma unroll
    for (int j = 0; j < 8; ++j) {
        ps += acc[j] * att_s[h * 64 + cbase + j];
        pd += acc[j] * att_d[h * 64 + cbase + j];
    }
#pragma unroll
    for (int off = 1; off < 8; off <<= 1) {
        ps += __shfl_xor(ps, off);
        pd += __shfl_xor(pd, off);
    }
    if ((cg & 7) == 0 && n < n_nodes) {
        asrc[n * 4 + h] = ps;
        adst[n * 4 + h] = pd;
    }
}

// ---------------------------------------------------------------------------
// GAT aggregation: one 64-lane wave per destination node.
// Pass 1: segment max of leaky_relu(a_src[s]+a_dst[n]) per head.
// Pass 2: denom += w, acc[h][lane] += w * hp[s, h*64+lane]; normalize at end.
// out = mean_h(acc/denom) + bias + residual(xin)
// ---------------------------------------------------------------------------
__global__ __launch_bounds__(64) void gat_agg_kernel(
    const float* __restrict__ hp, const float* __restrict__ asrc,
    const float* __restrict__ adst, const float* __restrict__ xin,
    const float* __restrict__ bias, const int* __restrict__ rowptr,
    const int* __restrict__ col, float* __restrict__ out, int n_nodes) {
    const int n = blockIdx.x;
    const int lane = threadIdx.x;
    const int start = rowptr[n], end = rowptr[n + 1];
    float ad[4];
#pragma unroll
    for (int h = 0; h < 4; ++h) ad[h] = adst[n * 4 + h];

    float m[4] = {-1e30f, -1e30f, -1e30f, -1e30f};
    for (int i = start + lane; i < end; i += 64) {
        int s = col[i];
#pragma unroll
        for (int h = 0; h < 4; ++h) {
            float l = asrc[s * 4 + h] + ad[h];
            l = l > 0.f ? l : NEG_SLOPE * l;
            m[h] = fmaxf(m[h], l);
        }
    }
#pragma unroll
    for (int off = 32; off > 0; off >>= 1) {
#pragma unroll
        for (int h = 0; h < 4; ++h) m[h] = fmaxf(m[h], __shfl_xor(m[h], off));
    }

    float den[4] = {0.f, 0.f, 0.f, 0.f};
    float acc[4] = {0.f, 0.f, 0.f, 0.f};
    for (int i = start; i < end; ++i) {
        int s = col[i];
        float w[4];
#pragma unroll
        for (int h = 0; h < 4; ++h) {
            float l = asrc[s * 4 + h] + ad[h];
            l = l > 0.f ? l : NEG_SLOPE * l;
            w[h] = __expf(l - m[h]);
            den[h] += w[h];
        }
        const float* hs = hp + (size_t)s * 256 + lane;
#pragma unroll
        for (int h = 0; h < 4; ++h) acc[h] += w[h] * hs[h * 64];
    }
    float r = 0.f;
#pragma unroll
    for (int h = 0; h < 4; ++h) r += acc[h] / (den[h] + 1e-16f);
    out[(size_t)n * 64 + lane] = 0.25f * r + bias[lane] + xin[(size_t)n * 64 + lane];
}

// ---------------------------------------------------------------------------
// Output MLP: 64 -> 64 (elu) -> 32 (elu) -> 8. One wave per node.
// ---------------------------------------------------------------------------
__global__ __launch_bounds__(64) void out_mlp_kernel(
    const float* __restrict__ h, const float* __restrict__ W1,
    const float* __restrict__ b1, const float* __restrict__ W2,
    const float* __restrict__ b2, const float* __restrict__ W3,
    const float* __restrict__ b3, float* __restrict__ out, int n_nodes) {
    const int n = blockIdx.x;
    const int t = threadIdx.x;
    __shared__ float s1[64], s2[64];
    s1[t] = h[(size_t)n * 64 + t];
    __syncthreads();
    float a = b1[t];
    for (int k = 0; k < 64; ++k) a += s1[k] * W1[k * 64 + t];
    s2[t] = elu_f(a);
    __syncthreads();
    float o2 = 0.f;
    if (t < 32) {
        float a2 = b2[t];
        for (int k = 0; k < 64; ++k) a2 += s2[k] * W2[k * 32 + t];
        o2 = elu_f(a2);
    }
    __syncthreads();
    if (t < 32) s1[t] = o2;
    __syncthreads();
    if (t < 8) {
        float a3 = b3[t];
        for (int k = 0; k < 32; ++k) a3 += s1[k] * W3[k * 8 + t];
        out[(size_t)n * 8 + t] = a3;
    }
}

// ---------------------------------------------------------------------------
extern "C" void kernel_launch(void* const* d_in, const int* in_sizes, int n_in,
                              void* d_out, int out_size, void* d_ws, size_t ws_size,
                              hipStream_t stream) {
    const float* x     = (const float*)d_in[0];
    const int*   ei    = (const int*)d_in[1];
    const float* Wenc1 = (const float*)d_in[2];
    const float* benc1 = (const float*)d_in[3];
    const float* Wenc2 = (const float*)d_in[4];
    const float* benc2 = (const float*)d_in[5];
    const float* Wg[3]   = {(const float*)d_in[6],  (const float*)d_in[10], (const float*)d_in[14]};
    const float* as_[3]  = {(const float*)d_in[7],  (const float*)d_in[11], (const float*)d_in[15]};
    const float* ad_[3]  = {(const float*)d_in[8],  (const float*)d_in[12], (const float*)d_in[16]};
    const float* bg[3]   = {(const float*)d_in[9],  (const float*)d_in[13], (const float*)d_in[17]};
    const float* Wo1 = (const float*)d_in[18];
    const float* bo1 = (const float*)d_in[19];
    const float* Wo2 = (const float*)d_in[20];
    const float* bo2 = (const float*)d_in[21];
    const float* Wo3 = (const float*)d_in[22];
    const float* bo3 = (const float*)d_in[23];

    const int N = in_sizes[0] / 8;
    const int E = in_sizes[1] / 2;
    const int Etot = E + N;

    // workspace layout (fp32 / int32)
    float* buf0 = (float*)d_ws;                 // N*64
    float* buf1 = buf0 + (size_t)N * 64;        // N*64
    float* hp   = buf1 + (size_t)N * 64;        // N*256
    float* asrc = hp + (size_t)N * 256;         // N*4
    float* adst = asrc + (size_t)N * 4;         // N*4
    int* rowptr = (int*)(adst + (size_t)N * 4); // N+1
    int* cursor = rowptr + (N + 2);             // N
    int* cnt    = cursor + N;                   // N
    int* col    = cnt + N;                      // Etot

    // ---- CSR build (once per call; graph is static across layers) ----
    zero_kernel<<<(N + 255) / 256, 256, 0, stream>>>(cnt, N);
    count_kernel<<<(Etot + 255) / 256, 256, 0, stream>>>(ei, E, Etot, cnt);
    scan_kernel<<<1, 1024, 0, stream>>>(cnt, rowptr, cursor, N);
    fill_kernel<<<(Etot + 255) / 256, 256, 0, stream>>>(ei, E, Etot, cursor, col);

    // ---- encoder ----
    encoder_kernel<<<(N + 255) / 256, 256, 0, stream>>>(x, Wenc1, benc1, Wenc2, benc2, buf0, N);

    // ---- 3 GAT layers (ping-pong buf0/buf1) ----
    float* bin = buf0;
    float* bout = buf1;
    for (int l = 0; l < 3; ++l) {
        gat_proj_kernel<<<(N + 7) / 8, 256, 0, stream>>>(bin, Wg[l], as_[l], ad_[l],
                                                         hp, asrc, adst, N);
        gat_agg_kernel<<<N, 64, 0, stream>>>(hp, asrc, adst, bin, bg[l], rowptr, col,
                                             bout, N);
        float* tmp = bin; bin = bout; bout = tmp;
    }

    // ---- output MLP (bin holds h3) ----
    out_mlp_kernel<<<N, 64, 0, stream>>>(bin, Wo1, bo1, Wo2, bo2, Wo3, bo3,
                                         (float*)d_out, N);
}

// Round 2
// 481.922 us; speedup vs baseline: 1.0446x; 1.0446x over previous
//
#include <hip/hip_runtime.h>
#include <cstdint>
#include <cstddef>

#define NEG_SLOPE 0.2f

__device__ __forceinline__ float elu_f(float x) {
    return x > 0.f ? x : expm1f(x);
}

// ---------------------------------------------------------------------------
// Encoder: h0 = elu(elu(x @ W1 + b1) @ W2 + b2), x:[N,8] -> [N,64]
// ---------------------------------------------------------------------------
__global__ void encoder_kernel(const float* __restrict__ x,
                               const float* __restrict__ W1, const float* __restrict__ b1,
                               const float* __restrict__ W2, const float* __restrict__ b2,
                               float* __restrict__ h0, int n_nodes) {
    int i = blockIdx.x * blockDim.x + threadIdx.x;
    if (i >= n_nodes) return;
    const float4* xp = (const float4*)(x + (size_t)i * 8);
    float4 x0 = xp[0], x1 = xp[1];
    float xi[8] = {x0.x, x0.y, x0.z, x0.w, x1.x, x1.y, x1.z, x1.w};
    float h1[32];
#pragma unroll
    for (int j = 0; j < 32; ++j) {
        float a = b1[j];
#pragma unroll
        for (int k = 0; k < 8; ++k) a += xi[k] * W1[k * 32 + j];
        h1[j] = elu_f(a);
    }
    float* dst = h0 + (size_t)i * 64;
    for (int j = 0; j < 64; ++j) {
        float a = b2[j];
#pragma unroll
        for (int k = 0; k < 32; ++k) a += h1[k] * W2[k * 64 + j];
        dst[j] = elu_f(a);
    }
}

// ---------------------------------------------------------------------------
// CSR build (by destination), reused across all 3 GAT layers.
// edge_index may be int32 or int64-viewed-as-int32-pairs; one-thread detect.
// ---------------------------------------------------------------------------
__global__ void zero_detect_kernel(const int* __restrict__ ei, int* __restrict__ cnt,
                                   int* __restrict__ flag, int n) {
    int i = blockIdx.x * blockDim.x + threadIdx.x;
    if (i < n) cnt[i] = 0;
    if (i == 0) {
        int acc = 0;
#pragma unroll
        for (int k = 0; k < 8; ++k) acc |= ei[2 * k + 1];
        flag[0] = (acc == 0) ? 1 : 0;  // high words all zero -> int64 layout
    }
}

__global__ void count_kernel(const int* __restrict__ ei, const int* __restrict__ flag,
                             int E, int Etot, int* __restrict__ cnt) {
    int e = blockIdx.x * blockDim.x + threadIdx.x;
    if (e >= Etot) return;
    int d;
    if (e < E) d = flag[0] ? ei[2 * (size_t)(E + e)] : ei[E + e];
    else       d = e - E;  // self loop
    atomicAdd(&cnt[d], 1);
}

#define SCAN_B 256
__global__ void scan1_kernel(const int* __restrict__ cnt, int* __restrict__ incl,
                             int* __restrict__ bsum, int n) {
    __shared__ int sd[SCAN_B];
    int t = threadIdx.x;
    int g = blockIdx.x * SCAN_B + t;
    int v = (g < n) ? cnt[g] : 0;
    sd[t] = v;
    __syncthreads();
    for (int off = 1; off < SCAN_B; off <<= 1) {
        int add = (t >= off) ? sd[t - off] : 0;
        __syncthreads();
        sd[t] += add;
        __syncthreads();
    }
    if (g < n) incl[g] = sd[t];
    if (t == SCAN_B - 1) bsum[blockIdx.x] = sd[SCAN_B - 1];
}

__global__ void scan2_kernel(const int* __restrict__ bsum, int* __restrict__ boff, int nb) {
    __shared__ int sd[256];
    int t = threadIdx.x;
    int v = (t < nb) ? bsum[t] : 0;
    sd[t] = v;
    __syncthreads();
    for (int off = 1; off < 256; off <<= 1) {
        int add = (t >= off) ? sd[t - off] : 0;
        __syncthreads();
        sd[t] += add;
        __syncthreads();
    }
    if (t < nb) boff[t] = sd[t] - v;  // exclusive block offset
}

__global__ void scan3_kernel(const int* __restrict__ incl, const int* __restrict__ boff,
                             const int* __restrict__ cnt, int* __restrict__ rowptr,
                             int* __restrict__ cursor, int n) {
    int i = blockIdx.x * SCAN_B + threadIdx.x;
    if (i >= n) return;
    int e = incl[i] + boff[blockIdx.x];
    rowptr[i + 1] = e;
    cursor[i] = e - cnt[i];
    if (i == 0) rowptr[0] = 0;
}

__global__ void fill_kernel(const int* __restrict__ ei, const int* __restrict__ flag,
                            int E, int Etot, int* __restrict__ cursor,
                            int* __restrict__ col) {
    int e = blockIdx.x * blockDim.x + threadIdx.x;
    if (e >= Etot) return;
    int s, d;
    if (e < E) {
        if (flag[0]) { s = ei[2 * (size_t)e]; d = ei[2 * (size_t)(E + e)]; }
        else         { s = ei[e];             d = ei[E + e]; }
    } else {
        s = d = e - E;
    }
    int pos = atomicAdd(&cursor[d], 1);
    col[pos] = s;
}

// ---------------------------------------------------------------------------
// GAT projection: hp = x @ W  ([N,64]x[64,256]) + per-head attention dots.
// Block = 256 threads = 8 nodes x 32 channel-groups (8 ch each).
// ---------------------------------------------------------------------------
__global__ __launch_bounds__(256) void gat_proj_kernel(
    const float* __restrict__ xin, const float* __restrict__ W,
    const float* __restrict__ att_s, const float* __restrict__ att_d,
    float* __restrict__ hp, float* __restrict__ asrc, float* __restrict__ adst,
    int n_nodes) {
    const int t = threadIdx.x;
    const int nl = t >> 5;   // local node 0..7
    const int cg = t & 31;   // channel group 0..31 (8 ch each)
    const int n0 = blockIdx.x * 8;
    __shared__ float xs[8][64];
    for (int i = t; i < 8 * 64; i += 256) {
        int nn = n0 + (i >> 6);
        xs[i >> 6][i & 63] = (nn < n_nodes) ? xin[(size_t)nn * 64 + (i & 63)] : 0.f;
    }
    __syncthreads();
    const int n = n0 + nl;
    float acc[8];
#pragma unroll
    for (int j = 0; j < 8; ++j) acc[j] = 0.f;
    const float* Wb = W + cg * 8;
    for (int k = 0; k < 64; ++k) {
        float xv = xs[nl][k];
        const float4* wp = (const float4*)(Wb + k * 256);
        float4 w0 = wp[0], w1 = wp[1];
        acc[0] += xv * w0.x; acc[1] += xv * w0.y;
        acc[2] += xv * w0.z; acc[3] += xv * w0.w;
        acc[4] += xv * w1.x; acc[5] += xv * w1.y;
        acc[6] += xv * w1.z; acc[7] += xv * w1.w;
    }
    if (n < n_nodes) {
        float4* op = (float4*)(hp + (size_t)n * 256 + cg * 8);
        op[0] = make_float4(acc[0], acc[1], acc[2], acc[3]);
        op[1] = make_float4(acc[4], acc[5], acc[6], acc[7]);
    }
    const int h = cg >> 3;
    const int cbase = (cg & 7) * 8;
    float ps = 0.f, pd = 0.f;
#pragma unroll
    for (int j = 0; j < 8; ++j) {
        ps += acc[j] * att_s[h * 64 + cbase + j];
        pd += acc[j] * att_d[h * 64 + cbase + j];
    }
#pragma unroll
    for (int off = 1; off < 8; off <<= 1) {
        ps += __shfl_xor(ps, off);
        pd += __shfl_xor(pd, off);
    }
    if ((cg & 7) == 0 && n < n_nodes) {
        asrc[n * 4 + h] = ps;
        adst[n * 4 + h] = pd;
    }
}

// ---------------------------------------------------------------------------
// GAT aggregation v2: 4 waves/block, one wave per dst node, single edge pass.
// No segment-max (softmax is shift-invariant; logits are O(1), clamp at 60).
// Chunk: lane j prefetches col + exp-weights for edge base+j; serial loop
// broadcasts via shfl; per edge ONE dwordx4 gather (lane l -> channels 4l..4l+3,
// head l/16). Cross-head mean via shfl_xor(16|32).
// ---------------------------------------------------------------------------
__global__ __launch_bounds__(256) void gat_agg_kernel(
    const float* __restrict__ hp, const float* __restrict__ asrc,
    const float* __restrict__ adst, const float* __restrict__ xin,
    const float* __restrict__ bias, const int* __restrict__ rowptr,
    const int* __restrict__ col, float* __restrict__ out, int n_nodes) {
    const int wid = threadIdx.x >> 6;
    const int lane = threadIdx.x & 63;
    const int n = blockIdx.x * 4 + wid;
    if (n >= n_nodes) return;
    const int hl = lane >> 4;  // this lane's head
    const float4 ad4 = *(const float4*)(adst + (size_t)n * 4);
    const int start = rowptr[n], end = rowptr[n + 1];

    float acc0 = 0.f, acc1 = 0.f, acc2 = 0.f, acc3 = 0.f, den = 0.f;
    for (int base = start; base < end; base += 64) {
        const int cnt = min(64, end - base);
        int c = 0;
        float4 w4 = make_float4(0.f, 0.f, 0.f, 0.f);
        if (base + lane < end) {
            c = col[base + lane];
            const float4 av = *(const float4*)(asrc + (size_t)c * 4);
            float l0 = av.x + ad4.x; l0 = l0 > 0.f ? l0 : NEG_SLOPE * l0;
            float l1 = av.y + ad4.y; l1 = l1 > 0.f ? l1 : NEG_SLOPE * l1;
            float l2 = av.z + ad4.z; l2 = l2 > 0.f ? l2 : NEG_SLOPE * l2;
            float l3 = av.w + ad4.w; l3 = l3 > 0.f ? l3 : NEG_SLOPE * l3;
            w4.x = __expf(fminf(l0, 60.f));
            w4.y = __expf(fminf(l1, 60.f));
            w4.z = __expf(fminf(l2, 60.f));
            w4.w = __expf(fminf(l3, 60.f));
        }
        for (int j = 0; j < cnt; ++j) {
            const int s = __shfl(c, j);
            const float wx = __shfl(w4.x, j);
            const float wy = __shfl(w4.y, j);
            const float wz = __shfl(w4.z, j);
            const float ww = __shfl(w4.w, j);
            const float w = (hl == 0) ? wx : (hl == 1) ? wy : (hl == 2) ? wz : ww;
            den += w;
            const float4 hv = *(const float4*)(hp + (size_t)s * 256 + lane * 4);
            acc0 += w * hv.x; acc1 += w * hv.y;
            acc2 += w * hv.z; acc3 += w * hv.w;
        }
    }
    const float inv = 1.f / (den + 1e-16f);
    float r0 = acc0 * inv, r1 = acc1 * inv, r2 = acc2 * inv, r3 = acc3 * inv;
    // sum the 4 heads (lanes l, l^16, l^32, l^48 hold the same channel group)
    r0 += __shfl_xor(r0, 16); r1 += __shfl_xor(r1, 16);
    r2 += __shfl_xor(r2, 16); r3 += __shfl_xor(r3, 16);
    r0 += __shfl_xor(r0, 32); r1 += __shfl_xor(r1, 32);
    r2 += __shfl_xor(r2, 32); r3 += __shfl_xor(r3, 32);
    if (lane < 16) {
        const int c4 = lane * 4;
        const float4 b4 = *(const float4*)(bias + c4);
        const float4 x4 = *(const float4*)(xin + (size_t)n * 64 + c4);
        float4 o;
        o.x = 0.25f * r0 + b4.x + x4.x;
        o.y = 0.25f * r1 + b4.y + x4.y;
        o.z = 0.25f * r2 + b4.z + x4.z;
        o.w = 0.25f * r3 + b4.w + x4.w;
        *(float4*)(out + (size_t)n * 64 + c4) = o;
    }
}

// ---------------------------------------------------------------------------
// Output MLP: 64 -> 64 (elu) -> 32 (elu) -> 8. 4 waves/block, shfl-based.
// ---------------------------------------------------------------------------
__global__ __launch_bounds__(256) void out_mlp_kernel(
    const float* __restrict__ h, const float* __restrict__ W1,
    const float* __restrict__ b1, const float* __restrict__ W2,
    const float* __restrict__ b2, const float* __restrict__ W3,
    const float* __restrict__ b3, float* __restrict__ out, int n_nodes) {
    const int wid = threadIdx.x >> 6;
    const int lane = threadIdx.x & 63;
    const int n = blockIdx.x * 4 + wid;
    if (n >= n_nodes) return;
    const float hv = h[(size_t)n * 64 + lane];
    float a = b1[lane];
#pragma unroll
    for (int k = 0; k < 64; ++k) a += __shfl(hv, k) * W1[k * 64 + lane];
    const float o1 = elu_f(a);
    const int c2 = lane & 31;
    float a2 = b2[c2];
#pragma unroll
    for (int k = 0; k < 64; ++k) a2 += __shfl(o1, k) * W2[k * 32 + c2];
    const float o2 = elu_f(a2);
    const int c3 = lane & 7;
    float a3 = b3[c3];
#pragma unroll
    for (int k = 0; k < 32; ++k) a3 += __shfl(o2, k) * W3[k * 8 + c3];
    if (lane < 8) out[(size_t)n * 8 + lane] = a3;
}

// ---------------------------------------------------------------------------
extern "C" void kernel_launch(void* const* d_in, const int* in_sizes, int n_in,
                              void* d_out, int out_size, void* d_ws, size_t ws_size,
                              hipStream_t stream) {
    const float* x     = (const float*)d_in[0];
    const int*   ei    = (const int*)d_in[1];
    const float* Wenc1 = (const float*)d_in[2];
    const float* benc1 = (const float*)d_in[3];
    const float* Wenc2 = (const float*)d_in[4];
    const float* benc2 = (const float*)d_in[5];
    const float* Wg[3]  = {(const float*)d_in[6],  (const float*)d_in[10], (const float*)d_in[14]};
    const float* as_[3] = {(const float*)d_in[7],  (const float*)d_in[11], (const float*)d_in[15]};
    const float* ad_[3] = {(const float*)d_in[8],  (const float*)d_in[12], (const float*)d_in[16]};
    const float* bg[3]  = {(const float*)d_in[9],  (const float*)d_in[13], (const float*)d_in[17]};
    const float* Wo1 = (const float*)d_in[18];
    const float* bo1 = (const float*)d_in[19];
    const float* Wo2 = (const float*)d_in[20];
    const float* bo2 = (const float*)d_in[21];
    const float* Wo3 = (const float*)d_in[22];
    const float* bo3 = (const float*)d_in[23];

    const int N = in_sizes[0] / 8;
    const int E = in_sizes[1] / 2;
    const int Etot = E + N;
    const int nblk = (N + SCAN_B - 1) / SCAN_B;

    // workspace layout (fp32 / int32)
    float* buf0 = (float*)d_ws;                  // N*64
    float* buf1 = buf0 + (size_t)N * 64;         // N*64
    float* hp   = buf1 + (size_t)N * 64;         // N*256
    float* asrc = hp + (size_t)N * 256;          // N*4
    float* adst = asrc + (size_t)N * 4;          // N*4
    int* rowptr = (int*)(adst + (size_t)N * 4);  // N+1 (+pad)
    int* cursor = rowptr + (N + 2);              // N
    int* cnt    = cursor + N;                    // N
    int* incl   = cnt + N;                       // N
    int* bsum   = incl + N;                      // 256
    int* boff   = bsum + 256;                    // 256
    int* flag   = boff + 256;                    // 1 (+pad)
    int* col    = flag + 2;                      // Etot

    // ---- CSR build (graph static across layers; rebuilt every call) ----
    zero_detect_kernel<<<(N + 255) / 256, 256, 0, stream>>>(ei, cnt, flag, N);
    count_kernel<<<(Etot + 255) / 256, 256, 0, stream>>>(ei, flag, E, Etot, cnt);
    scan1_kernel<<<nblk, SCAN_B, 0, stream>>>(cnt, incl, bsum, N);
    scan2_kernel<<<1, 256, 0, stream>>>(bsum, boff, nblk);
    scan3_kernel<<<nblk, SCAN_B, 0, stream>>>(incl, boff, cnt, rowptr, cursor, N);
    fill_kernel<<<(Etot + 255) / 256, 256, 0, stream>>>(ei, flag, E, Etot, cursor, col);

    // ---- encoder ----
    encoder_kernel<<<(N + 255) / 256, 256, 0, stream>>>(x, Wenc1, benc1, Wenc2, benc2, buf0, N);

    // ---- 3 GAT layers (ping-pong buf0/buf1) ----
    float* bin = buf0;
    float* bout = buf1;
    for (int l = 0; l < 3; ++l) {
        gat_proj_kernel<<<(N + 7) / 8, 256, 0, stream>>>(bin, Wg[l], as_[l], ad_[l],
                                                         hp, asrc, adst, N);
        gat_agg_kernel<<<(N + 3) / 4, 256, 0, stream>>>(hp, asrc, adst, bin, bg[l],
                                                        rowptr, col, bout, N);
        float* tmp = bin; bin = bout; bout = tmp;
    }

    // ---- output MLP (bin holds h3) ----
    out_mlp_kernel<<<(N + 3) / 4, 256, 0, stream>>>(bin, Wo1, bo1, Wo2, bo2, Wo3, bo3,
                                                    (float*)d_out, N);
}

// Round 3
// 408.022 us; speedup vs baseline: 1.2338x; 1.1811x over previous
//
#include <hip/hip_runtime.h>
#include <cstdint>
#include <cstddef>

#define NEG_SLOPE 0.2f

__device__ __forceinline__ float elu_f(float x) {
    return x > 0.f ? x : expm1f(x);
}

// ---------------------------------------------------------------------------
// Encoder: h0 = elu(elu(x @ W1 + b1) @ W2 + b2), x:[N,8] -> [N,64]
// ---------------------------------------------------------------------------
__global__ void encoder_kernel(const float* __restrict__ x,
                               const float* __restrict__ W1, const float* __restrict__ b1,
                               const float* __restrict__ W2, const float* __restrict__ b2,
                               float* __restrict__ h0, int n_nodes) {
    int i = blockIdx.x * blockDim.x + threadIdx.x;
    if (i >= n_nodes) return;
    const float4* xp = (const float4*)(x + (size_t)i * 8);
    float4 x0 = xp[0], x1 = xp[1];
    float xi[8] = {x0.x, x0.y, x0.z, x0.w, x1.x, x1.y, x1.z, x1.w};
    float h1[32];
#pragma unroll
    for (int j = 0; j < 32; ++j) {
        float a = b1[j];
#pragma unroll
        for (int k = 0; k < 8; ++k) a += xi[k] * W1[k * 32 + j];
        h1[j] = elu_f(a);
    }
    float* dst = h0 + (size_t)i * 64;
    for (int j = 0; j < 64; ++j) {
        float a = b2[j];
#pragma unroll
        for (int k = 0; k < 32; ++k) a += h1[k] * W2[k * 64 + j];
        dst[j] = elu_f(a);
    }
}

// ---------------------------------------------------------------------------
// CSR build (by destination), reused across all 3 GAT layers.
// ---------------------------------------------------------------------------
__global__ void zero_detect_kernel(const int* __restrict__ ei, int* __restrict__ cnt,
                                   int* __restrict__ flag, int n) {
    int i = blockIdx.x * blockDim.x + threadIdx.x;
    if (i < n) cnt[i] = 0;
    if (i == 0) {
        int acc = 0;
#pragma unroll
        for (int k = 0; k < 8; ++k) acc |= ei[2 * k + 1];
        flag[0] = (acc == 0) ? 1 : 0;  // high words all zero -> int64 layout
    }
}

__global__ void count_kernel(const int* __restrict__ ei, const int* __restrict__ flag,
                             int E, int Etot, int* __restrict__ cnt) {
    int e = blockIdx.x * blockDim.x + threadIdx.x;
    if (e >= Etot) return;
    int d;
    if (e < E) d = flag[0] ? ei[2 * (size_t)(E + e)] : ei[E + e];
    else       d = e - E;  // self loop
    atomicAdd(&cnt[d], 1);
}

#define SCAN_B 256
__global__ void scan1_kernel(const int* __restrict__ cnt, int* __restrict__ incl,
                             int* __restrict__ bsum, int n) {
    __shared__ int sd[SCAN_B];
    int t = threadIdx.x;
    int g = blockIdx.x * SCAN_B + t;
    int v = (g < n) ? cnt[g] : 0;
    sd[t] = v;
    __syncthreads();
    for (int off = 1; off < SCAN_B; off <<= 1) {
        int add = (t >= off) ? sd[t - off] : 0;
        __syncthreads();
        sd[t] += add;
        __syncthreads();
    }
    if (g < n) incl[g] = sd[t];
    if (t == SCAN_B - 1) bsum[blockIdx.x] = sd[SCAN_B - 1];
}

__global__ void scan2_kernel(const int* __restrict__ bsum, int* __restrict__ boff, int nb) {
    __shared__ int sd[256];
    int t = threadIdx.x;
    int v = (t < nb) ? bsum[t] : 0;
    sd[t] = v;
    __syncthreads();
    for (int off = 1; off < 256; off <<= 1) {
        int add = (t >= off) ? sd[t - off] : 0;
        __syncthreads();
        sd[t] += add;
        __syncthreads();
    }
    if (t < nb) boff[t] = sd[t] - v;  // exclusive block offset
}

__global__ void scan3_kernel(const int* __restrict__ incl, const int* __restrict__ boff,
                             const int* __restrict__ cnt, int* __restrict__ rowptr,
                             int* __restrict__ cursor, int n) {
    int i = blockIdx.x * SCAN_B + threadIdx.x;
    if (i >= n) return;
    int e = incl[i] + boff[blockIdx.x];
    rowptr[i + 1] = e;
    cursor[i] = e - cnt[i];
    if (i == 0) rowptr[0] = 0;
}

__global__ void fill_kernel(const int* __restrict__ ei, const int* __restrict__ flag,
                            int E, int Etot, int* __restrict__ cursor,
                            int* __restrict__ col) {
    int e = blockIdx.x * blockDim.x + threadIdx.x;
    if (e >= Etot) return;
    int s, d;
    if (e < E) {
        if (flag[0]) { s = ei[2 * (size_t)e]; d = ei[2 * (size_t)(E + e)]; }
        else         { s = ei[e];             d = ei[E + e]; }
    } else {
        s = d = e - E;
    }
    int pos = atomicAdd(&cursor[d], 1);
    col[pos] = s;
}

// ---------------------------------------------------------------------------
// GAT projection v3: LDS outer-product GEMM.
// Block = 32 nodes x 256 cols, 256 threads; micro-tile 4 nodes x 8 cols.
// W (64KB) + x^T (8KB) staged to LDS once; k-loop has ZERO global traffic.
// B-read bank fix: quad-parity s swaps the two float4 halves so each
// ds_read_b128 tiles all 32 banks at depth 4 (read-side only, flat storage).
// acc[i][0..3] = cols cLo..cLo+3, acc[i][4..7] = cols cHi..cHi+3.
// ---------------------------------------------------------------------------
__global__ __launch_bounds__(256) void gat_proj_kernel(
    const float* __restrict__ xin, const float* __restrict__ W,
    const float* __restrict__ att_s, const float* __restrict__ att_d,
    float* __restrict__ hp, float* __restrict__ asrc, float* __restrict__ adst,
    int n_nodes) {
    __shared__ float Wlds[64 * 256];   // [k][c] flat, 64 KB
    __shared__ float xsT[64 * 32];     // [k][node] , 8 KB
    const int t = threadIdx.x;
    const int n0 = blockIdx.x * 32;

    // stage W: flat coalesced copy (16K floats / 256 threads = 16 float4 each)
#pragma unroll
    for (int j = 0; j < 16; ++j) {
        const int f = j * 1024 + t * 4;
        *(float4*)(Wlds + f) = *(const float4*)(W + f);
    }
    // stage x^T: thread t -> node nn = t&31, k-base kb = (t>>5)*8 (8 k's)
    {
        const int nn = t & 31;
        const int kb = (t >> 5) * 8;
        float4 v0 = make_float4(0.f, 0.f, 0.f, 0.f), v1 = v0;
        if (n0 + nn < n_nodes) {
            const float4* xr = (const float4*)(xin + (size_t)(n0 + nn) * 64 + kb);
            v0 = xr[0]; v1 = xr[1];
        }
        xsT[(kb + 0) * 32 + nn] = v0.x; xsT[(kb + 1) * 32 + nn] = v0.y;
        xsT[(kb + 2) * 32 + nn] = v0.z; xsT[(kb + 3) * 32 + nn] = v0.w;
        xsT[(kb + 4) * 32 + nn] = v1.x; xsT[(kb + 5) * 32 + nn] = v1.y;
        xsT[(kb + 6) * 32 + nn] = v1.z; xsT[(kb + 7) * 32 + nn] = v1.w;
    }
    __syncthreads();

    const int cg = t & 31;         // col group: 8 cols at cg*8
    const int ng = t >> 5;         // node group: 4 nodes at ng*4
    const int s = (cg >> 2) & 1;   // bank-tiling parity
    const int cLo = cg * 8 + 4 * s;        // cols of acc[i][0..3]
    const int cHi = cg * 8 + 4 - 4 * s;    // cols of acc[i][4..7]

    float acc[4][8];
#pragma unroll
    for (int i = 0; i < 4; ++i)
#pragma unroll
        for (int j = 0; j < 8; ++j) acc[i][j] = 0.f;

#pragma unroll 8
    for (int k = 0; k < 64; ++k) {
        const float4 a4 = *(const float4*)(xsT + k * 32 + ng * 4);
        const float4 bl = *(const float4*)(Wlds + k * 256 + cLo);
        const float4 bh = *(const float4*)(Wlds + k * 256 + cHi);
        const float av[4] = {a4.x, a4.y, a4.z, a4.w};
#pragma unroll
        for (int i = 0; i < 4; ++i) {
            acc[i][0] += av[i] * bl.x; acc[i][1] += av[i] * bl.y;
            acc[i][2] += av[i] * bl.z; acc[i][3] += av[i] * bl.w;
            acc[i][4] += av[i] * bh.x; acc[i][5] += av[i] * bh.y;
            acc[i][6] += av[i] * bh.z; acc[i][7] += av[i] * bh.w;
        }
    }

    // epilogue: store hp + fused attention dots
    const int h = cg >> 3;              // head of this col group
    const int chLo = cLo & 63;          // channel within head
    const int chHi = cHi & 63;
    float ps[4], pd[4];
#pragma unroll
    for (int i = 0; i < 4; ++i) {
        const int n = n0 + ng * 4 + i;
        if (n < n_nodes) {
            *(float4*)(hp + (size_t)n * 256 + cLo) =
                make_float4(acc[i][0], acc[i][1], acc[i][2], acc[i][3]);
            *(float4*)(hp + (size_t)n * 256 + cHi) =
                make_float4(acc[i][4], acc[i][5], acc[i][6], acc[i][7]);
        }
        float p = 0.f, q = 0.f;
#pragma unroll
        for (int j = 0; j < 4; ++j) {
            p += acc[i][j] * att_s[h * 64 + chLo + j];
            p += acc[i][4 + j] * att_s[h * 64 + chHi + j];
            q += acc[i][j] * att_d[h * 64 + chLo + j];
            q += acc[i][4 + j] * att_d[h * 64 + chHi + j];
        }
        ps[i] = p; pd[i] = q;
    }
    // reduce over the 8 lanes of this col group (cg&7), same ng
#pragma unroll
    for (int off = 1; off < 8; off <<= 1) {
#pragma unroll
        for (int i = 0; i < 4; ++i) {
            ps[i] += __shfl_xor(ps[i], off);
            pd[i] += __shfl_xor(pd[i], off);
        }
    }
    if ((cg & 7) == 0) {
#pragma unroll
        for (int i = 0; i < 4; ++i) {
            const int n = n0 + ng * 4 + i;
            if (n < n_nodes) {
                asrc[n * 4 + h] = ps[i];
                adst[n * 4 + h] = pd[i];
            }
        }
    }
}

// ---------------------------------------------------------------------------
// GAT aggregation: 4 waves/block, one wave per dst node, single edge pass.
// ---------------------------------------------------------------------------
__global__ __launch_bounds__(256) void gat_agg_kernel(
    const float* __restrict__ hp, const float* __restrict__ asrc,
    const float* __restrict__ adst, const float* __restrict__ xin,
    const float* __restrict__ bias, const int* __restrict__ rowptr,
    const int* __restrict__ col, float* __restrict__ out, int n_nodes) {
    const int wid = threadIdx.x >> 6;
    const int lane = threadIdx.x & 63;
    const int n = blockIdx.x * 4 + wid;
    if (n >= n_nodes) return;
    const int hl = lane >> 4;  // this lane's head
    const float4 ad4 = *(const float4*)(adst + (size_t)n * 4);
    const int start = rowptr[n], end = rowptr[n + 1];

    float acc0 = 0.f, acc1 = 0.f, acc2 = 0.f, acc3 = 0.f, den = 0.f;
    for (int base = start; base < end; base += 64) {
        const int cnt = min(64, end - base);
        int c = 0;
        float4 w4 = make_float4(0.f, 0.f, 0.f, 0.f);
        if (base + lane < end) {
            c = col[base + lane];
            const float4 av = *(const float4*)(asrc + (size_t)c * 4);
            float l0 = av.x + ad4.x; l0 = l0 > 0.f ? l0 : NEG_SLOPE * l0;
            float l1 = av.y + ad4.y; l1 = l1 > 0.f ? l1 : NEG_SLOPE * l1;
            float l2 = av.z + ad4.z; l2 = l2 > 0.f ? l2 : NEG_SLOPE * l2;
            float l3 = av.w + ad4.w; l3 = l3 > 0.f ? l3 : NEG_SLOPE * l3;
            w4.x = __expf(fminf(l0, 60.f));
            w4.y = __expf(fminf(l1, 60.f));
            w4.z = __expf(fminf(l2, 60.f));
            w4.w = __expf(fminf(l3, 60.f));
        }
        for (int j = 0; j < cnt; ++j) {
            const int s = __shfl(c, j);
            const float wx = __shfl(w4.x, j);
            const float wy = __shfl(w4.y, j);
            const float wz = __shfl(w4.z, j);
            const float ww = __shfl(w4.w, j);
            const float w = (hl == 0) ? wx : (hl == 1) ? wy : (hl == 2) ? wz : ww;
            den += w;
            const float4 hv = *(const float4*)(hp + (size_t)s * 256 + lane * 4);
            acc0 += w * hv.x; acc1 += w * hv.y;
            acc2 += w * hv.z; acc3 += w * hv.w;
        }
    }
    const float inv = 1.f / (den + 1e-16f);
    float r0 = acc0 * inv, r1 = acc1 * inv, r2 = acc2 * inv, r3 = acc3 * inv;
    r0 += __shfl_xor(r0, 16); r1 += __shfl_xor(r1, 16);
    r2 += __shfl_xor(r2, 16); r3 += __shfl_xor(r3, 16);
    r0 += __shfl_xor(r0, 32); r1 += __shfl_xor(r1, 32);
    r2 += __shfl_xor(r2, 32); r3 += __shfl_xor(r3, 32);
    if (lane < 16) {
        const int c4 = lane * 4;
        const float4 b4 = *(const float4*)(bias + c4);
        const float4 x4 = *(const float4*)(xin + (size_t)n * 64 + c4);
        float4 o;
        o.x = 0.25f * r0 + b4.x + x4.x;
        o.y = 0.25f * r1 + b4.y + x4.y;
        o.z = 0.25f * r2 + b4.z + x4.z;
        o.w = 0.25f * r3 + b4.w + x4.w;
        *(float4*)(out + (size_t)n * 64 + c4) = o;
    }
}

// ---------------------------------------------------------------------------
// Output MLP: 64 -> 64 (elu) -> 32 (elu) -> 8. 4 waves/block, shfl-based.
// ---------------------------------------------------------------------------
__global__ __launch_bounds__(256) void out_mlp_kernel(
    const float* __restrict__ h, const float* __restrict__ W1,
    const float* __restrict__ b1, const float* __restrict__ W2,
    const float* __restrict__ b2, const float* __restrict__ W3,
    const float* __restrict__ b3, float* __restrict__ out, int n_nodes) {
    const int wid = threadIdx.x >> 6;
    const int lane = threadIdx.x & 63;
    const int n = blockIdx.x * 4 + wid;
    if (n >= n_nodes) return;
    const float hv = h[(size_t)n * 64 + lane];
    float a = b1[lane];
#pragma unroll
    for (int k = 0; k < 64; ++k) a += __shfl(hv, k) * W1[k * 64 + lane];
    const float o1 = elu_f(a);
    const int c2 = lane & 31;
    float a2 = b2[c2];
#pragma unroll
    for (int k = 0; k < 64; ++k) a2 += __shfl(o1, k) * W2[k * 32 + c2];
    const float o2 = elu_f(a2);
    const int c3 = lane & 7;
    float a3 = b3[c3];
#pragma unroll
    for (int k = 0; k < 32; ++k) a3 += __shfl(o2, k) * W3[k * 8 + c3];
    if (lane < 8) out[(size_t)n * 8 + lane] = a3;
}

// ---------------------------------------------------------------------------
extern "C" void kernel_launch(void* const* d_in, const int* in_sizes, int n_in,
                              void* d_out, int out_size, void* d_ws, size_t ws_size,
                              hipStream_t stream) {
    const float* x     = (const float*)d_in[0];
    const int*   ei    = (const int*)d_in[1];
    const float* Wenc1 = (const float*)d_in[2];
    const float* benc1 = (const float*)d_in[3];
    const float* Wenc2 = (const float*)d_in[4];
    const float* benc2 = (const float*)d_in[5];
    const float* Wg[3]  = {(const float*)d_in[6],  (const float*)d_in[10], (const float*)d_in[14]};
    const float* as_[3] = {(const float*)d_in[7],  (const float*)d_in[11], (const float*)d_in[15]};
    const float* ad_[3] = {(const float*)d_in[8],  (const float*)d_in[12], (const float*)d_in[16]};
    const float* bg[3]  = {(const float*)d_in[9],  (const float*)d_in[13], (const float*)d_in[17]};
    const float* Wo1 = (const float*)d_in[18];
    const float* bo1 = (const float*)d_in[19];
    const float* Wo2 = (const float*)d_in[20];
    const float* bo2 = (const float*)d_in[21];
    const float* Wo3 = (const float*)d_in[22];
    const float* bo3 = (const float*)d_in[23];

    const int N = in_sizes[0] / 8;
    const int E = in_sizes[1] / 2;
    const int Etot = E + N;
    const int nblk = (N + SCAN_B - 1) / SCAN_B;

    float* buf0 = (float*)d_ws;                  // N*64
    float* buf1 = buf0 + (size_t)N * 64;         // N*64
    float* hp   = buf1 + (size_t)N * 64;         // N*256
    float* asrc = hp + (size_t)N * 256;          // N*4
    float* adst = asrc + (size_t)N * 4;          // N*4
    int* rowptr = (int*)(adst + (size_t)N * 4);  // N+1 (+pad)
    int* cursor = rowptr + (N + 2);              // N
    int* cnt    = cursor + N;                    // N
    int* incl   = cnt + N;                       // N
    int* bsum   = incl + N;                      // 256
    int* boff   = bsum + 256;                    // 256
    int* flag   = boff + 256;                    // 1 (+pad)
    int* col    = flag + 2;                      // Etot

    // ---- CSR build ----
    zero_detect_kernel<<<(N + 255) / 256, 256, 0, stream>>>(ei, cnt, flag, N);
    count_kernel<<<(Etot + 255) / 256, 256, 0, stream>>>(ei, flag, E, Etot, cnt);
    scan1_kernel<<<nblk, SCAN_B, 0, stream>>>(cnt, incl, bsum, N);
    scan2_kernel<<<1, 256, 0, stream>>>(bsum, boff, nblk);
    scan3_kernel<<<nblk, SCAN_B, 0, stream>>>(incl, boff, cnt, rowptr, cursor, N);
    fill_kernel<<<(Etot + 255) / 256, 256, 0, stream>>>(ei, flag, E, Etot, cursor, col);

    // ---- encoder ----
    encoder_kernel<<<(N + 255) / 256, 256, 0, stream>>>(x, Wenc1, benc1, Wenc2, benc2, buf0, N);

    // ---- 3 GAT layers (ping-pong buf0/buf1) ----
    float* bin = buf0;
    float* bout = buf1;
    for (int l = 0; l < 3; ++l) {
        gat_proj_kernel<<<(N + 31) / 32, 256, 0, stream>>>(bin, Wg[l], as_[l], ad_[l],
                                                           hp, asrc, adst, N);
        gat_agg_kernel<<<(N + 3) / 4, 256, 0, stream>>>(hp, asrc, adst, bin, bg[l],
                                                        rowptr, col, bout, N);
        float* tmp = bin; bin = bout; bout = tmp;
    }

    // ---- output MLP (bin holds h3) ----
    out_mlp_kernel<<<(N + 3) / 4, 256, 0, stream>>>(bin, Wo1, bo1, Wo2, bo2, Wo3, bo3,
                                                    (float*)d_out, N);
}